// Round 3
// baseline (124.665 us; speedup 1.0000x reference)
//
#include <hip/hip_runtime.h>

// Attention branch of the reference is the constant 1.0 (softmax over a
// size-1 axis). Survivor:
//   out[b, o*576 + p] = 1 + gelu( conv3x3(x4, local_w, groups=2, pad=1)*s[o] + t[o] )
// s[o] = bnc1_gamma[o]*rsqrt(1+eps), t[o] = bnc1_beta[o]; NCHW flat order.
//
// V4 = V3 with the forced VGPR cap removed (spill-proof).
//   V2: __launch_bounds__(256,6) -> 85-VGPR cap  -> heavy spill, resid ~16us
//   V3: __launch_bounds__(256,4) -> 128-VGPR cap -> still spills, resid ~13us
//   V4: __launch_bounds__(256)   -> no cap, compiler allocates organically.
// Also: #pragma unroll 1 on the channel loop bounds in-flight x-loads at ~9
// values, so the organic live set (~36 wt + ~18 x + 4 acc + addr ~ 80 VGPR)
// lands at ~6 waves/EU without any forced bound.
//
// Structure: grid = 2*128*9 blocks (b, o, 64-position spatial chunk),
// block = 256 thr = 16 quads (4 adjacent outputs) x 16 channel-chunks (4 ch);
// float4 x-row loads (3 load instr / 12 FMA), weights as 9 aligned dwordx4,
// 4.25KB LDS cross-chunk reduce (conflict-free both sides).

__global__ __launch_bounds__(256) void fused_conv_gelu(
    const float* __restrict__ x,    // (2,128,24,24) flat
    const float* __restrict__ lw,   // (128,64,3,3) flat
    const float* __restrict__ gam,  // (128,)
    const float* __restrict__ bet,  // (128,)
    float* __restrict__ out)        // (2,576,128) flat == (2,128,24,24) flat
{
    const int bi   = blockIdx.x;        // 0..2303
    const int qblk = bi % 9;            // spatial chunk: positions [qblk*64, qblk*64+64)
    const int rest = bi / 9;
    const int o    = rest & 127;
    const int b    = rest >> 7;
    const int g    = o >> 6;

    const int tid = threadIdx.x;
    const int q   = tid & 15;           // quad index: 4 consecutive positions
    const int cs  = tid >> 4;           // channel chunk: input channels cs*4 .. cs*4+3

    const int pos0 = qblk * 64 + q * 4; // 24 % 4 == 0 -> quad never crosses a row
    const int h    = pos0 / 24;
    const int w0   = pos0 - h * 24;     // in {0,4,8,12,16,20}

    const bool lz   = (w0 == 0);        // left tap of output w0 is out of row
    const bool rz   = (w0 == 20);       // right tap of output w0+3 is out of row
    const int  loff = lz ? 0 : -1;      // clamped (always in-bounds) addresses
    const int  roff = rz ? 3 : 4;

    // ---- weights: 4 channels x 9 taps = 36 contiguous floats, 144B-aligned ----
    const float* __restrict__ wp = lw + o * 576 + cs * 36;
    float wv[36];
#pragma unroll
    for (int k = 0; k < 9; ++k) {
        const float4 t4 = *reinterpret_cast<const float4*>(wp + 4 * k);
        wv[4 * k + 0] = t4.x; wv[4 * k + 1] = t4.y;
        wv[4 * k + 2] = t4.z; wv[4 * k + 3] = t4.w;
    }

    const float* __restrict__ xg = x + ((b * 128 + g * 64) + cs * 4) * 576;

    float acc0 = 0.f, acc1 = 0.f, acc2 = 0.f, acc3 = 0.f;

#pragma unroll 1
    for (int c = 0; c < 4; ++c) {
        const float* __restrict__ xc = xg + c * 576;
#pragma unroll
        for (int dh = 0; dh < 3; ++dh) {
            const int hh = h + dh - 1;
            if ((unsigned)hh < 24u) {   // uniform-true in interior blocks
                const float* __restrict__ row = xc + hh * 24 + w0; // 16B aligned
                const float4 m4 = *reinterpret_cast<const float4*>(row);
                float x0 = row[loff]; if (lz) x0 = 0.f;
                float x5 = row[roff]; if (rz) x5 = 0.f;
                const float wt0 = wv[c * 9 + dh * 3 + 0];
                const float wt1 = wv[c * 9 + dh * 3 + 1];
                const float wt2 = wv[c * 9 + dh * 3 + 2];
                acc0 = fmaf(x0,   wt0, acc0);
                acc0 = fmaf(m4.x, wt1, acc0);
                acc0 = fmaf(m4.y, wt2, acc0);
                acc1 = fmaf(m4.x, wt0, acc1);
                acc1 = fmaf(m4.y, wt1, acc1);
                acc1 = fmaf(m4.z, wt2, acc1);
                acc2 = fmaf(m4.y, wt0, acc2);
                acc2 = fmaf(m4.z, wt1, acc2);
                acc2 = fmaf(m4.w, wt2, acc2);
                acc3 = fmaf(m4.z, wt0, acc3);
                acc3 = fmaf(m4.w, wt1, acc3);
                acc3 = fmaf(x5,   wt2, acc3);
            }
        }
    }

    // ---- cross-chunk reduction: 16 partials per output position ----
    __shared__ float red[16][68];       // 68-stride: conflict-free on both sides
    *reinterpret_cast<float4*>(&red[cs][q * 4]) =
        make_float4(acc0, acc1, acc2, acc3);   // (cs*68+q*4)*4B is 16B aligned
    __syncthreads();

    if (tid < 64) {
        float s = 0.f;
#pragma unroll
        for (int k = 0; k < 16; ++k) s += red[k][tid];  // stride-1 lanes: no conflict
        const float scale = gam[o] * rsqrtf(1.0f + 1e-5f);
        const float shift = bet[o];
        const float y  = fmaf(s, scale, shift);
        const float gl = 0.5f * y * (1.0f + erff(y * 0.70710678118654752f));
        out[b * 73728 + o * 576 + qblk * 64 + tid] = 1.0f + gl;
    }
}

extern "C" void kernel_launch(void* const* d_in, const int* in_sizes, int n_in,
                              void* d_out, int out_size, void* d_ws, size_t ws_size,
                              hipStream_t stream) {
    const float* x   = (const float*)d_in[0];   // x
    const float* lw  = (const float*)d_in[9];   // local_w
    const float* gam = (const float*)d_in[10];  // bnc1_gamma
    const float* bet = (const float*)d_in[11];  // bnc1_beta
    float* out = (float*)d_out;

    fused_conv_gelu<<<dim3(2304), dim3(256), 0, stream>>>(x, lw, gam, bet, out);
}

// Round 4
// 94.056 us; speedup vs baseline: 1.3254x; 1.3254x over previous
//
#include <hip/hip_runtime.h>

// Attention branch of the reference is the constant 1.0 (softmax over a
// size-1 axis). Survivor:
//   out[b, o*576 + p] = 1 + gelu( conv3x3(x4, local_w, groups=2, pad=1)*s[o] + t[o] )
// s[o] = bnc1_gamma[o]*rsqrt(1+eps), t[o] = bnc1_beta[o]; NCHW flat order.
//
// V5 = V3 body, spill-free by construction:
//   V2: (256,6) -> 85-VGPR cap  -> spill, resid ~16us
//   V3: (256,4) -> 128-VGPR cap -> spill, resid ~13us
//   V4: unroll 1 -> wv[] runtime-indexed -> DEMOTED TO SCRATCH (VGPR=32,
//       FETCH 46MB / WRITE 85MB of scratch traffic, kernel 51us) -- rule #20.
//   V5: full unroll (all wv indices compile-time) + __launch_bounds__(256)
//       with NO min-wave arg -> no cap, no spill; organic ~130-200 VGPR
//       still gives >= 2 waves/EU, above V1's 2.25.
//
// Structure: grid = 2*128*9 blocks (b, o, 64-position spatial chunk),
// block = 256 thr = 16 quads (4 adjacent outputs) x 16 channel-chunks (4 ch);
// float4 x-row loads (3 load instr / 12 FMA), weights as 9 aligned dwordx4
// held in VGPRs, 4.25KB LDS cross-chunk reduce (conflict-free both sides).

__global__ __launch_bounds__(256) void fused_conv_gelu(
    const float* __restrict__ x,    // (2,128,24,24) flat
    const float* __restrict__ lw,   // (128,64,3,3) flat
    const float* __restrict__ gam,  // (128,)
    const float* __restrict__ bet,  // (128,)
    float* __restrict__ out)        // (2,576,128) flat == (2,128,24,24) flat
{
    const int bi   = blockIdx.x;        // 0..2303
    const int qblk = bi % 9;            // spatial chunk: positions [qblk*64, qblk*64+64)
    const int rest = bi / 9;
    const int o    = rest & 127;
    const int b    = rest >> 7;
    const int g    = o >> 6;

    const int tid = threadIdx.x;
    const int q   = tid & 15;           // quad index: 4 consecutive positions
    const int cs  = tid >> 4;           // channel chunk: input channels cs*4 .. cs*4+3

    const int pos0 = qblk * 64 + q * 4; // 24 % 4 == 0 -> quad never crosses a row
    const int h    = pos0 / 24;
    const int w0   = pos0 - h * 24;     // in {0,4,8,12,16,20}

    const bool lz   = (w0 == 0);        // left tap of output w0 is out of row
    const bool rz   = (w0 == 20);       // right tap of output w0+3 is out of row
    const int  loff = lz ? 0 : -1;      // clamped (always in-bounds) addresses
    const int  roff = rz ? 3 : 4;

    // ---- weights: 4 channels x 9 taps = 36 contiguous floats, 144B-aligned.
    // Fully static indexing everywhere below -> guaranteed VGPR-resident.
    const float* __restrict__ wp = lw + o * 576 + cs * 36;
    float wv[36];
#pragma unroll
    for (int k = 0; k < 9; ++k) {
        const float4 t4 = *reinterpret_cast<const float4*>(wp + 4 * k);
        wv[4 * k + 0] = t4.x; wv[4 * k + 1] = t4.y;
        wv[4 * k + 2] = t4.z; wv[4 * k + 3] = t4.w;
    }

    const float* __restrict__ xg = x + ((b * 128 + g * 64) + cs * 4) * 576;

    float acc0 = 0.f, acc1 = 0.f, acc2 = 0.f, acc3 = 0.f;

#pragma unroll
    for (int c = 0; c < 4; ++c) {
        const float* __restrict__ xc = xg + c * 576;
#pragma unroll
        for (int dh = 0; dh < 3; ++dh) {
            const int hh = h + dh - 1;
            if ((unsigned)hh < 24u) {   // uniform-true in interior blocks
                const float* __restrict__ row = xc + hh * 24 + w0; // 16B aligned
                const float4 m4 = *reinterpret_cast<const float4*>(row);
                float x0 = row[loff]; if (lz) x0 = 0.f;
                float x5 = row[roff]; if (rz) x5 = 0.f;
                const float wt0 = wv[c * 9 + dh * 3 + 0];
                const float wt1 = wv[c * 9 + dh * 3 + 1];
                const float wt2 = wv[c * 9 + dh * 3 + 2];
                acc0 = fmaf(x0,   wt0, acc0);
                acc0 = fmaf(m4.x, wt1, acc0);
                acc0 = fmaf(m4.y, wt2, acc0);
                acc1 = fmaf(m4.x, wt0, acc1);
                acc1 = fmaf(m4.y, wt1, acc1);
                acc1 = fmaf(m4.z, wt2, acc1);
                acc2 = fmaf(m4.y, wt0, acc2);
                acc2 = fmaf(m4.z, wt1, acc2);
                acc2 = fmaf(m4.w, wt2, acc2);
                acc3 = fmaf(m4.z, wt0, acc3);
                acc3 = fmaf(m4.w, wt1, acc3);
                acc3 = fmaf(x5,   wt2, acc3);
            }
        }
    }

    // ---- cross-chunk reduction: 16 partials per output position ----
    __shared__ float red[16][68];       // 68-stride: conflict-free on both sides
    *reinterpret_cast<float4*>(&red[cs][q * 4]) =
        make_float4(acc0, acc1, acc2, acc3);   // (cs*68+q*4)*4B is 16B aligned
    __syncthreads();

    if (tid < 64) {
        float s = 0.f;
#pragma unroll
        for (int k = 0; k < 16; ++k) s += red[k][tid];  // stride-1 lanes: no conflict
        const float scale = gam[o] * rsqrtf(1.0f + 1e-5f);
        const float shift = bet[o];
        const float y  = fmaf(s, scale, shift);
        const float gl = 0.5f * y * (1.0f + erff(y * 0.70710678118654752f));
        out[b * 73728 + o * 576 + qblk * 64 + tid] = 1.0f + gl;
    }
}

extern "C" void kernel_launch(void* const* d_in, const int* in_sizes, int n_in,
                              void* d_out, int out_size, void* d_ws, size_t ws_size,
                              hipStream_t stream) {
    const float* x   = (const float*)d_in[0];   // x
    const float* lw  = (const float*)d_in[9];   // local_w
    const float* gam = (const float*)d_in[10];  // bnc1_gamma
    const float* bet = (const float*)d_in[11];  // bnc1_beta
    float* out = (float*)d_out;

    fused_conv_gelu<<<dim3(2304), dim3(256), 0, stream>>>(x, lw, gam, bet, out);
}

// Round 5
// 91.734 us; speedup vs baseline: 1.3590x; 1.0253x over previous
//
#include <hip/hip_runtime.h>

// Attention branch of the reference is the constant 1.0 (softmax over a
// size-1 axis). Survivor:
//   out[b, o*576 + p] = 1 + gelu( conv3x3(x4, local_w, groups=2, pad=1)*s[o] + t[o] )
// s[o] = bnc1_gamma[o]*rsqrt(1+eps), t[o] = bnc1_beta[o]; NCHW flat order.
//
// V6 = V1's launch shape (256 blocks = 1/CU, 576 thr = 9 waves) + quad-vector
// inner loop. History: V1 87.3us (576 scalar loads + 576 cndmask per wave);
// V2/V3 forced-cap spill (93-95); V4 runtime-indexed wv[] -> scratch (124);
// V5 spill-free but 2304-block structure (94): per-block overheads x9 and
// 16x-redundant VMEM weight loads ate the quad savings.
// V6: threads = 144 quads x 4 channel-chunks(16ch). Per channel-row one
// aligned float4 + 2 clamped scalars -> 12 FMA (144 x-load instr/wave, 4x
// fewer than V1). Weights staged once to LDS (coalesced), read as broadcast
// ds_read_b128 (off the VMEM pipe). Boundary = 6 weight-muls + 2 cndmask per
// channel. One 4-way LDS reduce per block. No VGPR cap, no runtime-indexed
// register arrays, unroll 4 bounds in-flight loads.

__global__ __launch_bounds__(576, 1) void fused_conv_gelu(
    const float* __restrict__ x,    // (2,128,24,24) flat
    const float* __restrict__ lw,   // (128,64,3,3) flat
    const float* __restrict__ gam,  // (128,)
    const float* __restrict__ bet,  // (128,)
    float* __restrict__ out)        // (2,576,128) flat == (2,128,24,24) flat
{
    const int bi = blockIdx.x;          // 0..255
    const int b  = bi >> 7;
    const int o  = bi & 127;
    const int g  = o >> 6;

    const int t  = threadIdx.x;         // 0..575
    const int cs = t / 144;             // channel chunk: channels cs*16 .. cs*16+15
    const int q  = t - cs * 144;        // quad id: output positions 4q .. 4q+3
    const int h  = q / 6;               // 0..23
    const int w0 = (q - h * 6) * 4;     // {0,4,8,12,16,20}

    // ---- stage this o's 576 weights into LDS, padded [64][12] for b128 reads
    __shared__ float wlds[64 * 12];     // 3 KB
    __shared__ float red[4][576];       // 9 KB, 4-way partial sums
    {
        const int c = t / 9, k = t - c * 9;     // t < 576 always
        wlds[c * 12 + k] = lw[o * 576 + t];
    }
    __syncthreads();

    // boundary handling: row masks fold into weights, col edges into 2 selects
    const float m0 = (h > 0)  ? 1.0f : 0.0f;    // dh=0 row valid
    const float m2 = (h < 23) ? 1.0f : 0.0f;    // dh=2 row valid
    const int   hm = (h > 0)  ? h - 1 : 0;      // clamped (in-bounds) addresses
    const int   hp = (h < 23) ? h + 1 : 23;
    const bool  lz = (w0 == 0), rz = (w0 == 20);
    const int   loff = lz ? 0 : -1;
    const int   roff = rz ? 3 : 4;

    const float* __restrict__ xg = x + (b * 128 + g * 64 + cs * 16) * 576;

    float acc0 = 0.f, acc1 = 0.f, acc2 = 0.f, acc3 = 0.f;

#define CONV_ROW(RP, T0, T1, T2)                                        \
    {                                                                   \
        const float4 m4 = *reinterpret_cast<const float4*>(RP);         \
        float xl = (RP)[loff]; if (lz) xl = 0.f;                        \
        float xr = (RP)[roff]; if (rz) xr = 0.f;                        \
        acc0 = fmaf(xl,   T0, acc0);                                    \
        acc0 = fmaf(m4.x, T1, acc0);                                    \
        acc0 = fmaf(m4.y, T2, acc0);                                    \
        acc1 = fmaf(m4.x, T0, acc1);                                    \
        acc1 = fmaf(m4.y, T1, acc1);                                    \
        acc1 = fmaf(m4.z, T2, acc1);                                    \
        acc2 = fmaf(m4.y, T0, acc2);                                    \
        acc2 = fmaf(m4.z, T1, acc2);                                    \
        acc2 = fmaf(m4.w, T2, acc2);                                    \
        acc3 = fmaf(m4.z, T0, acc3);                                    \
        acc3 = fmaf(m4.w, T1, acc3);                                    \
        acc3 = fmaf(xr,   T2, acc3);                                    \
    }

#pragma unroll 4
    for (int cc = 0; cc < 16; ++cc) {
        const float* __restrict__ xc = xg + cc * 576;
        const int c = cs * 16 + cc;
        // taps: dh=0 -> wA.x,y,z (mask m0) | dh=1 -> wA.w,wB.x,wB.y | dh=2 -> wB.z,wB.w,w8 (mask m2)
        const float4 wA = *reinterpret_cast<const float4*>(&wlds[c * 12]);
        const float4 wB = *reinterpret_cast<const float4*>(&wlds[c * 12 + 4]);
        const float  w8 = wlds[c * 12 + 8];

        CONV_ROW(xc + hm * 24 + w0, wA.x * m0, wA.y * m0, wA.z * m0);
        CONV_ROW(xc + h  * 24 + w0, wA.w,      wB.x,      wB.y);
        CONV_ROW(xc + hp * 24 + w0, wB.z * m2, wB.w * m2, w8   * m2);
    }
#undef CONV_ROW

    // ---- 4-way cross-chunk reduction ----
    *reinterpret_cast<float4*>(&red[cs][4 * q]) =
        make_float4(acc0, acc1, acc2, acc3);    // 16B aligned, conflict-free
    __syncthreads();

    const float s = red[0][t] + red[1][t] + red[2][t] + red[3][t]; // stride-1 lanes
    const float scale = gam[o] * rsqrtf(1.0f + 1e-5f);
    const float shift = bet[o];
    const float y  = fmaf(s, scale, shift);
    const float gl = 0.5f * y * (1.0f + erff(y * 0.70710678118654752f));
    out[b * 73728 + o * 576 + t] = 1.0f + gl;
}

extern "C" void kernel_launch(void* const* d_in, const int* in_sizes, int n_in,
                              void* d_out, int out_size, void* d_ws, size_t ws_size,
                              hipStream_t stream) {
    const float* x   = (const float*)d_in[0];   // x
    const float* lw  = (const float*)d_in[9];   // local_w
    const float* gam = (const float*)d_in[10];  // bnc1_gamma
    const float* bet = (const float*)d_in[11];  // bnc1_beta
    float* out = (float*)d_out;

    fused_conv_gelu<<<dim3(256), dim3(576), 0, stream>>>(x, lw, gam, bet, out);
}

// Round 6
// 87.241 us; speedup vs baseline: 1.4290x; 1.0515x over previous
//
#include <hip/hip_runtime.h>

// Attention branch of the reference is the constant 1.0 (softmax over a
// size-1 axis). Survivor:
//   out[b, o*576 + p] = 1 + gelu( conv3x3(x4, local_w, groups=2, pad=1)*s[o] + t[o] )
// s[o] = bnc1_gamma[o]*rsqrt(1+eps), t[o] = bnc1_beta[o]; NCHW flat order.
//
// V7 = V1's inner loop verbatim + occupancy fix.
// History: V1 87.3 (1 blk/CU, 2.25 waves/SIMD, ~40% latency stall);
// V2/V3 forced-VGPR-cap spill; V4 runtime-indexed regs -> scratch;
// V5/V6 quad-float4 restructures -- addressing VALU ate the savings.
// V7: keep V1's 2-VALU/MAC body (shared-base imm-offset taps, scalar-pipe
// weights) and raise waves/SIMD instead: 768 blocks = (b, o, pos-third);
// 576 thr = 3 wave-aligned ic-groups (192 = exactly 3 waves) x 192 positions.
// csw via readfirstlane is wave-uniform -> all control flow scalar, weight
// addresses stay uniform. 3-way LDS reduce (2.3 KB). 2-3 blocks/CU resident
// -> 4.5-6.75 waves/SIMD.

__global__ __launch_bounds__(576) void fused_conv_gelu(
    const float* __restrict__ x,    // (2,128,24,24) flat
    const float* __restrict__ lw,   // (128,64,3,3) flat
    const float* __restrict__ gam,  // (128,)
    const float* __restrict__ bet,  // (128,)
    float* __restrict__ out)        // (2,576,128) flat == (2,128,24,24) flat
{
    const int bi    = blockIdx.x;       // 0..767
    const int third = bi % 3;           // position chunk [third*192, third*192+192)
    const int rest  = bi / 3;
    const int o     = rest & 127;
    const int b     = rest >> 7;
    const int g     = o >> 6;

    const int t    = threadIdx.x;       // 0..575
    const int csw  = __builtin_amdgcn_readfirstlane(t / 192); // wave-uniform: waves 0-2|3-5|6-8
    const int p    = t - csw * 192;     // 0..191
    const int pos  = third * 192 + p;   // 0..575
    const int h    = pos / 24;
    const int w    = pos - h * 24;

    const float* __restrict__ xb = x  + (b * 128 + g * 64) * 576;
    const float* __restrict__ wb = lw + o * 576;

    // tap validity masks (channel-invariant) -- V1 verbatim
    bool val[9];
#pragma unroll
    for (int dh = 0; dh < 3; ++dh)
#pragma unroll
        for (int dw = 0; dw < 3; ++dw) {
            const int hh = h + dh - 1, ww = w + dw - 1;
            val[dh * 3 + dw] = (hh >= 0) && (hh < 24) && (ww >= 0) && (ww < 24);
        }

    float acc = 0.0f;

    // ---- edge channels i=0 (csw 0) / i=63 (csw 2): clamped in-bounds addressing
    if (csw == 0 || csw == 2) {         // uniform branch
        const int i = (csw == 0) ? 0 : 63;
        const float* __restrict__ xi = xb + i * 576;
        const float* __restrict__ wi = wb + i * 9;
#pragma unroll
        for (int dh = 0; dh < 3; ++dh)
#pragma unroll
            for (int dw = 0; dw < 3; ++dw) {
                const int tp = dh * 3 + dw;
                const int hh = min(max(h + dh - 1, 0), 23);
                const int ww = min(max(w + dw - 1, 0), 23);
                const float xv = xi[hh * 24 + ww];
                acc = fmaf(val[tp] ? xv : 0.0f, wi[tp], acc);
            }
    }

    // ---- main channels: V1 body verbatim, compile-time bounds per csw.
    // Address range rel. xb: [1*576 + 0 - 25, 62*576 + 575 + 25] -- in-bounds.
#define MAIN_LOOP(LO, HI)                                               \
    _Pragma("unroll 2")                                                 \
    for (int i = (LO); i < (HI); ++i) {                                 \
        const float* __restrict__ xi = xb + i * 576 + pos;              \
        const float* __restrict__ wi = wb + i * 9;                      \
        _Pragma("unroll")                                               \
        for (int dh = 0; dh < 3; ++dh)                                  \
            _Pragma("unroll")                                           \
            for (int dw = 0; dw < 3; ++dw) {                            \
                const int tp = dh * 3 + dw;                             \
                const float xv = xi[(dh - 1) * 24 + (dw - 1)];          \
                acc = fmaf(val[tp] ? xv : 0.0f, wi[tp], acc);           \
            }                                                           \
    }

    if (csw == 0)      { MAIN_LOOP(1, 22) }     // + edge i=0  -> 22 ch
    else if (csw == 1) { MAIN_LOOP(22, 43) }    //             -> 21 ch
    else               { MAIN_LOOP(43, 63) }    // + edge i=63 -> 21 ch
#undef MAIN_LOOP

    // ---- 3-way cross-group reduction ----
    __shared__ float red[3][192];       // 2.3 KB; lanes stride-1: conflict-free
    red[csw][p] = acc;
    __syncthreads();

    if (t < 192) {
        const float s = red[0][t] + red[1][t] + red[2][t];
        const float scale = gam[o] * rsqrtf(1.0f + 1e-5f);
        const float shift = bet[o];
        const float y  = fmaf(s, scale, shift);
        const float gl = 0.5f * y * (1.0f + erff(y * 0.70710678118654752f));
        out[b * 73728 + o * 576 + third * 192 + t] = 1.0f + gl;
    }
}

extern "C" void kernel_launch(void* const* d_in, const int* in_sizes, int n_in,
                              void* d_out, int out_size, void* d_ws, size_t ws_size,
                              hipStream_t stream) {
    const float* x   = (const float*)d_in[0];   // x
    const float* lw  = (const float*)d_in[9];   // local_w
    const float* gam = (const float*)d_in[10];  // bnc1_gamma
    const float* bet = (const float*)d_in[11];  // bnc1_beta
    float* out = (float*)d_out;

    fused_conv_gelu<<<dim3(768), dim3(576), 0, stream>>>(x, lw, gam, bet, out);
}